// Round 4
// baseline (2694.166 us; speedup 1.0000x reference)
//
#include <hip/hip_runtime.h>
#include <hip/hip_bf16.h>

#define Bn 2
#define Ln 2048
#define DIN 256
#define Hn 8
#define DEPTH 32
#define QT 128
#define KT 32
#define NKT (Ln / KT)
#define TS 34          // padded LDS tile row stride (floats): float2-friendly, 2-way max
#define SST (KT + 1)   // padded score row stride: conflict-free column scans

// ---------------------------------------------------------------------------
// Kernel 1: fully fused  (QKV projection + masked online-softmax attention).
// Grid (qtile=16, h=8, b=2) = 256 blocks, 512 threads.
// Writes attention output (pre-Wo) to d_out as FP32. Uses NO workspace.
// ---------------------------------------------------------------------------
__global__ __launch_bounds__(512) void fused_attn_kernel(
    const float* __restrict__ Xq, const float* __restrict__ Xk,
    const float* __restrict__ Xv, const int* __restrict__ mask,
    const float* __restrict__ Wq, const float* __restrict__ bq,
    const float* __restrict__ Wk, const float* __restrict__ bk,
    const float* __restrict__ Wv, const float* __restrict__ bv,
    float* __restrict__ out)
{
    __shared__ float Qs[QT * TS];          // 17.0 KB  (pre-scaled by 1/sqrt(depth))
    __shared__ float Ks[KT * TS];          // 4.25 KB
    __shared__ float Vs[KT * TS];          // 4.25 KB
    __shared__ float Ss[QT * SST];         // 16.5 KB
    __shared__ float mrow[QT], lrow[QT], arow[QT];
    __shared__ int mk[KT];                 // total ~44.7 KB

    const int t  = threadIdx.x;
    const int d  = t & 31;                 // head-dim column 0..31
    const int rg = t >> 5;                 // row group 0..15
    const int q0 = blockIdx.x * QT;
    const int h  = blockIdx.y;
    const int b  = blockIdx.z;
    const int hc = h * DEPTH + d;          // column within d_model

    // ---- Q-tile projection (fold in 1/sqrt(32)) ----
    {
        const float bqv = bq[hc];
        for (int i = 0; i < 8; ++i) {
            const int r = rg + 16 * i;
            const float* x = Xq + ((size_t)(b * Ln + q0 + r)) * DIN;
            float acc = bqv;
            #pragma unroll 8
            for (int k = 0; k < DIN; ++k) acc = fmaf(x[k], Wq[k * DIN + hc], acc);
            Qs[r * TS + d] = acc * 0.17677669529663687f;
        }
    }
    if (t < QT) { mrow[t] = -INFINITY; lrow[t] = 0.f; }
    float o_acc[8];
    #pragma unroll
    for (int i = 0; i < 8; ++i) o_acc[i] = 0.f;

    const float bkv = bk[hc], bvv = bv[hc];

    for (int kt = 0; kt < NKT; ++kt) {
        const int k0 = kt * KT;
        // ---- K/V tile projection into LDS ----
        #pragma unroll
        for (int i = 0; i < 2; ++i) {
            const int r = rg + 16 * i;
            const float* xk = Xk + ((size_t)(b * Ln + k0 + r)) * DIN;
            const float* xv = Xv + ((size_t)(b * Ln + k0 + r)) * DIN;
            float aK = bkv, aV = bvv;
            #pragma unroll 4
            for (int k = 0; k < DIN; ++k) {
                const float w1 = Wk[k * DIN + hc];
                const float w2 = Wv[k * DIN + hc];
                aK = fmaf(xk[k], w1, aK);
                aV = fmaf(xv[k], w2, aV);
            }
            Ks[r * TS + d] = aK;
            Vs[r * TS + d] = aV;
        }
        if (t < KT) mk[t] = mask[b * Ln + k0 + t];
        __syncthreads();                                   // S1

        // ---- scores: S[r][k] = (Q/sqrt32) . K,  masked with finite NEG_INF ----
        for (int idx = t; idx < QT * KT; idx += 512) {
            const int r = idx >> 5, k = idx & (KT - 1);
            const float2* qv = (const float2*)(Qs + r * TS);
            const float2* kv = (const float2*)(Ks + k * TS);
            float s = 0.f;
            #pragma unroll
            for (int j = 0; j < 16; ++j) {
                float2 a = qv[j], c = kv[j];
                s += a.x * c.x + a.y * c.y;
            }
            Ss[r * SST + k] = mk[k] ? s : -4294967296.0f;  // float32(-2^32+1)
        }
        __syncthreads();                                   // S2

        // ---- per-row running max + rescale factor ----
        if (t < QT) {
            float tm = -INFINITY;
            #pragma unroll 8
            for (int k = 0; k < KT; ++k) tm = fmaxf(tm, Ss[t * SST + k]);
            const float nm = fmaxf(mrow[t], tm);
            arow[t] = __expf(mrow[t] - nm);                // exp(-inf)=0 on first tile
            mrow[t] = nm;
        }
        __syncthreads();                                   // S3

        // ---- P = exp(S - m) ----
        for (int idx = t; idx < QT * KT; idx += 512) {
            const int r = idx >> 5, k = idx & (KT - 1);
            Ss[r * SST + k] = __expf(Ss[r * SST + k] - mrow[r]);
        }
        __syncthreads();                                   // S4

        // ---- l update ----
        if (t < QT) {
            float rs = 0.f;
            #pragma unroll 8
            for (int k = 0; k < KT; ++k) rs += Ss[t * SST + k];
            lrow[t] = arow[t] * lrow[t] + rs;
        }
        // ---- O = alpha*O + P @ V ----
        #pragma unroll
        for (int i = 0; i < 8; ++i) {
            const int r = rg + 16 * i;
            const float a = arow[r];
            float acc = o_acc[i] * a;
            const float* pr = Ss + r * SST;
            const float* vc = Vs + d;
            #pragma unroll 8
            for (int k = 0; k < KT; ++k) acc = fmaf(pr[k], vc[k * TS], acc);
            o_acc[i] = acc;
        }
        __syncthreads();                                   // S5
    }

    // ---- epilogue: normalize, write attn-out (pre-Wo) to d_out as FP32 ----
    #pragma unroll
    for (int i = 0; i < 8; ++i) {
        const int r = rg + 16 * i;
        out[((size_t)(b * Ln + q0 + r)) * DIN + hc] = o_acc[i] / lrow[r];
    }
}

// ---------------------------------------------------------------------------
// Kernel 2: in-place output projection on d_out (fp32 -> fp32).
// Each block owns 4 disjoint rows: stage them in LDS, sync, then overwrite.
// ---------------------------------------------------------------------------
__global__ __launch_bounds__(256) void out_proj_kernel(
    const float* __restrict__ Wo, const float* __restrict__ bo,
    float* __restrict__ out)
{
    __shared__ float xr[4][DIN];
    const int col = threadIdx.x;
    const int r0 = blockIdx.x * 4;
    #pragma unroll
    for (int rr = 0; rr < 4; ++rr)
        xr[rr][col] = out[(size_t)(r0 + rr) * DIN + col];
    __syncthreads();
    const float bb = bo[col];
    float a0 = bb, a1 = bb, a2 = bb, a3 = bb;
    #pragma unroll 4
    for (int k = 0; k < DIN; ++k) {
        const float w = Wo[k * DIN + col];
        a0 = fmaf(xr[0][k], w, a0);
        a1 = fmaf(xr[1][k], w, a1);
        a2 = fmaf(xr[2][k], w, a2);
        a3 = fmaf(xr[3][k], w, a3);
    }
    float* o = out + (size_t)r0 * DIN + col;
    o[0]       = a0;
    o[DIN]     = a1;
    o[2 * DIN] = a2;
    o[3 * DIN] = a3;
}

// ---------------------------------------------------------------------------
// Probe: fill output with a distinctive constant (signals a failed host-side
// assumption check; exact under both fp32 and bf16 readback at odd slots).
// ---------------------------------------------------------------------------
__global__ void fill_kernel(float* __restrict__ out, int n, float c) {
    int i = blockIdx.x * 256 + threadIdx.x;
    if (i < n) out[i] = c;
}

extern "C" void kernel_launch(void* const* d_in, const int* in_sizes, int n_in,
                              void* d_out, int out_size, void* d_ws, size_t ws_size,
                              hipStream_t stream) {
    // ---- host-side assumption probes (in_sizes/out_size are host memory) ----
    static const int expect[12] = {
        Bn * Ln * DIN, Bn * Ln * DIN, Bn * Ln * DIN, Bn * Ln,   // q, k, v, mask
        DIN * DIN, DIN, DIN * DIN, DIN, DIN * DIN, DIN,         // Wq,bq,Wk,bk,Wv,bv
        DIN * DIN, DIN                                          // Wo, bo
    };
    int fail = -1;
    if (n_in != 12) fail = 0;
    else {
        for (int i = 0; i < 12; ++i)
            if (in_sizes[i] != expect[i]) { fail = 1 + i; break; }
        if (fail < 0 && out_size != Bn * Ln * DIN) fail = 13;
    }
    if (fail >= 0) {
        const float c = (float)(64 << fail);   // 64 * 2^fail, exact in bf16 & fp32
        fill_kernel<<<(out_size + 255) / 256, 256, 0, stream>>>((float*)d_out,
                                                                out_size, c);
        return;
    }

    const float* Xq = (const float*)d_in[0];
    const float* Xk = (const float*)d_in[1];
    const float* Xv = (const float*)d_in[2];
    const int* mask = (const int*)d_in[3];
    const float* Wq = (const float*)d_in[4];
    const float* bq = (const float*)d_in[5];
    const float* Wk = (const float*)d_in[6];
    const float* bk = (const float*)d_in[7];
    const float* Wv = (const float*)d_in[8];
    const float* bv = (const float*)d_in[9];
    const float* Wo = (const float*)d_in[10];
    const float* bo = (const float*)d_in[11];
    float* out = (float*)d_out;

    fused_attn_kernel<<<dim3(Ln / QT, Hn, Bn), 512, 0, stream>>>(
        Xq, Xk, Xv, mask, Wq, bq, Wk, bk, Wv, bv, out);
    out_proj_kernel<<<Bn * Ln / 4, 256, 0, stream>>>(Wo, bo, out);
}

// Round 5
// 418.975 us; speedup vs baseline: 6.4304x; 6.4304x over previous
//
#include <hip/hip_runtime.h>
#include <hip/hip_bf16.h>

#define Bn 2
#define Ln 2048
#define DIN 256
#define Hn 8
#define DEPTH 32
#define MR (Bn * Ln)                    // 4096 rows
#define SCALE 0.17677669529663687f      // 1/sqrt(32)
#define NEGC (-4294967296.0f)           // float32(-2^32+1)

// ===========================================================================
// FAST PATH (needs ws >= 12.6 MB): QKV-proj GEMM -> flash attention -> out-proj
// ===========================================================================

// ---- Kernel A: QKV projection, row-major X @ W + b -> head-major [b,h,L,32].
// Grid (MR/16, 3), 256 threads. Thread: 4 rows x 4 cols, float4 everywhere.
__global__ __launch_bounds__(256) void qkv_proj(
    const float* __restrict__ Xq, const float* __restrict__ Xk, const float* __restrict__ Xv,
    const float* __restrict__ Wq, const float* __restrict__ bq,
    const float* __restrict__ Wk, const float* __restrict__ bk,
    const float* __restrict__ Wv, const float* __restrict__ bv,
    float* __restrict__ Qd, float* __restrict__ Kd, float* __restrict__ Vd)
{
    const int p = blockIdx.y;
    const float* X = p == 0 ? Xq : (p == 1 ? Xk : Xv);
    const float* W = p == 0 ? Wq : (p == 1 ? Wk : Wv);
    const float* bs = p == 0 ? bq : (p == 1 ? bk : bv);
    float* dst = p == 0 ? Qd : (p == 1 ? Kd : Vd);
    const float sc = p == 0 ? SCALE : 1.0f;

    const int t = threadIdx.x;
    const int c0 = (t & 63) * 4;
    const int r0 = blockIdx.x * 16 + (t >> 6) * 4;

    float acc[4][4];
    {
        float4 bb = *(const float4*)(bs + c0);
        #pragma unroll
        for (int i = 0; i < 4; ++i) {
            acc[i][0] = bb.x; acc[i][1] = bb.y; acc[i][2] = bb.z; acc[i][3] = bb.w;
        }
    }
    for (int k4 = 0; k4 < DIN; k4 += 4) {
        float4 xr[4];
        #pragma unroll
        for (int i = 0; i < 4; ++i)
            xr[i] = *(const float4*)(X + (size_t)(r0 + i) * DIN + k4);
        #pragma unroll
        for (int kk = 0; kk < 4; ++kk) {
            float4 w = *(const float4*)(W + (size_t)(k4 + kk) * DIN + c0);
            #pragma unroll
            for (int i = 0; i < 4; ++i) {
                float xv = ((const float*)&xr[i])[kk];
                acc[i][0] = fmaf(xv, w.x, acc[i][0]);
                acc[i][1] = fmaf(xv, w.y, acc[i][1]);
                acc[i][2] = fmaf(xv, w.z, acc[i][2]);
                acc[i][3] = fmaf(xv, w.w, acc[i][3]);
            }
        }
    }
    const int h = c0 >> 5, dd = c0 & 31;
    #pragma unroll
    for (int i = 0; i < 4; ++i) {
        const int row = r0 + i, b = row >> 11, q = row & (Ln - 1);
        float4 o = make_float4(acc[i][0] * sc, acc[i][1] * sc, acc[i][2] * sc, acc[i][3] * sc);
        *(float4*)(dst + (((size_t)(b * Hn + h)) * Ln + q) * DEPTH + dd) = o;
    }
}

// ---- Kernel B: flash attention, fp32. 256 threads, 64 queries/(b,h) per block.
// Q pre-scaled. Writes O in place over the Q buffer (block-private rows).
__global__ __launch_bounds__(256) void flash_attn(
    const float* __restrict__ Qd, const float* __restrict__ Kd,
    const float* __restrict__ Vd, const int* __restrict__ mask,
    float* __restrict__ Od)
{
    __shared__ float Qs[64 * 36];     // [q][d], stride 36: 16B-aligned float4
    __shared__ float Ks[64 * 36];
    __shared__ float Vs[64 * 36];
    __shared__ float Ps[64 * 68];     // [q][k], stride 68
    __shared__ float pred[64 * 17];   // per-row partials [q][16]
    __shared__ float mrow[64], lrow[64], arow[64];
    __shared__ int mk[64];

    const int t = threadIdx.x;
    const int b = blockIdx.z, h = blockIdx.y, q0 = blockIdx.x * 64;
    const size_t headoff = ((size_t)(b * Hn + h)) * Ln * DEPTH;

    // stage Q tile (64x32): thread -> row t>>2, 8 floats at (t&3)*8
    {
        const int q = t >> 2, d8 = (t & 3) * 8;
        const float* g = Qd + headoff + (size_t)(q0 + q) * DEPTH + d8;
        *(float4*)(Qs + q * 36 + d8)     = *(const float4*)g;
        *(float4*)(Qs + q * 36 + d8 + 4) = *(const float4*)(g + 4);
    }
    if (t < 64) { mrow[t] = -INFINITY; lrow[t] = 0.f; }

    float o[2][4];
    #pragma unroll
    for (int i = 0; i < 2; ++i)
        #pragma unroll
        for (int j = 0; j < 4; ++j) o[i][j] = 0.f;

    const int kg = t & 15, qg4 = (t >> 4) * 4;   // S-phase mapping
    const int qg = t >> 3, dg = t & 7, d4 = dg * 4;  // PV mapping

    for (int kt = 0; kt < Ln / 64; ++kt) {
        const int k0 = kt * 64;
        // ---- stage K, V, mask ----
        {
            const int q = t >> 2, d8 = (t & 3) * 8;
            const float* gk = Kd + headoff + (size_t)(k0 + q) * DEPTH + d8;
            const float* gv = Vd + headoff + (size_t)(k0 + q) * DEPTH + d8;
            *(float4*)(Ks + q * 36 + d8)     = *(const float4*)gk;
            *(float4*)(Ks + q * 36 + d8 + 4) = *(const float4*)(gk + 4);
            *(float4*)(Vs + q * 36 + d8)     = *(const float4*)gv;
            *(float4*)(Vs + q * 36 + d8 + 4) = *(const float4*)(gv + 4);
        }
        if (t < 64) mk[t] = mask[b * Ln + k0 + t];
        __syncthreads();                                        // S1

        // ---- S-phase: s[i][j] = Q[qg4+i] . K[kg+16j]  (k-cols strided by 16) ----
        float s[4][4];
        #pragma unroll
        for (int i = 0; i < 4; ++i)
            #pragma unroll
            for (int j = 0; j < 4; ++j) s[i][j] = 0.f;
        #pragma unroll
        for (int dq = 0; dq < DEPTH; dq += 4) {
            float4 qv[4], kv[4];
            #pragma unroll
            for (int i = 0; i < 4; ++i) qv[i] = *(const float4*)(Qs + (qg4 + i) * 36 + dq);
            #pragma unroll
            for (int j = 0; j < 4; ++j) kv[j] = *(const float4*)(Ks + (kg + 16 * j) * 36 + dq);
            #pragma unroll
            for (int i = 0; i < 4; ++i)
                #pragma unroll
                for (int j = 0; j < 4; ++j) {
                    s[i][j] = fmaf(qv[i].x, kv[j].x, s[i][j]);
                    s[i][j] = fmaf(qv[i].y, kv[j].y, s[i][j]);
                    s[i][j] = fmaf(qv[i].z, kv[j].z, s[i][j]);
                    s[i][j] = fmaf(qv[i].w, kv[j].w, s[i][j]);
                }
        }
        // mask + per-thread row maxes
        {
            int mj[4];
            #pragma unroll
            for (int j = 0; j < 4; ++j) mj[j] = mk[kg + 16 * j];
            #pragma unroll
            for (int i = 0; i < 4; ++i) {
                float pm = -INFINITY;
                #pragma unroll
                for (int j = 0; j < 4; ++j) {
                    float v = mj[j] ? s[i][j] : NEGC;
                    s[i][j] = v;
                    pm = fmaxf(pm, v);
                }
                pred[(qg4 + i) * 17 + kg] = pm;
            }
        }
        __syncthreads();                                        // S2

        if (t < 64) {
            float m0 = pred[t * 17];
            #pragma unroll
            for (int g = 1; g < 16; ++g) m0 = fmaxf(m0, pred[t * 17 + g]);
            const float nm = fmaxf(mrow[t], m0);
            arow[t] = __expf(mrow[t] - nm);
            mrow[t] = nm;
        }
        __syncthreads();                                        // S3

        // ---- P = exp(S - m), write to Ps, per-thread row sums ----
        #pragma unroll
        for (int i = 0; i < 4; ++i) {
            const float mi = mrow[qg4 + i];
            float ps = 0.f;
            #pragma unroll
            for (int j = 0; j < 4; ++j) {
                float pp = __expf(s[i][j] - mi);
                Ps[(qg4 + i) * 68 + kg + 16 * j] = pp;
                ps += pp;
            }
            pred[(qg4 + i) * 17 + kg] = ps;
        }
        __syncthreads();                                        // S4

        if (t < 64) {
            float rs = 0.f;
            #pragma unroll
            for (int g = 0; g < 16; ++g) rs += pred[t * 17 + g];
            lrow[t] = arow[t] * lrow[t] + rs;
        }
        // ---- PV: O[2 rows][4 cols] += P . V, with alpha rescale ----
        {
            const float a0 = arow[2 * qg], a1 = arow[2 * qg + 1];
            #pragma unroll
            for (int j = 0; j < 4; ++j) { o[0][j] *= a0; o[1][j] *= a1; }
            #pragma unroll 4
            for (int k = 0; k < 64; k += 4) {
                float4 p0 = *(const float4*)(Ps + (2 * qg) * 68 + k);
                float4 p1 = *(const float4*)(Ps + (2 * qg + 1) * 68 + k);
                #pragma unroll
                for (int kk = 0; kk < 4; ++kk) {
                    float4 vv = *(const float4*)(Vs + (k + kk) * 36 + d4);
                    const float f0 = ((const float*)&p0)[kk];
                    const float f1 = ((const float*)&p1)[kk];
                    o[0][0] = fmaf(f0, vv.x, o[0][0]); o[0][1] = fmaf(f0, vv.y, o[0][1]);
                    o[0][2] = fmaf(f0, vv.z, o[0][2]); o[0][3] = fmaf(f0, vv.w, o[0][3]);
                    o[1][0] = fmaf(f1, vv.x, o[1][0]); o[1][1] = fmaf(f1, vv.y, o[1][1]);
                    o[1][2] = fmaf(f1, vv.z, o[1][2]); o[1][3] = fmaf(f1, vv.w, o[1][3]);
                }
            }
        }
        __syncthreads();                                        // S5
    }

    // epilogue: normalize, write head-major (in-place over Q rows of this block)
    #pragma unroll
    for (int i = 0; i < 2; ++i) {
        const int q = 2 * qg + i;
        const float inv = 1.0f / lrow[q];
        float4 res = make_float4(o[i][0] * inv, o[i][1] * inv, o[i][2] * inv, o[i][3] * inv);
        *(float4*)(Od + headoff + (size_t)(q0 + q) * DEPTH + d4) = res;
    }
}

// ---- Kernel C: out projection, head-major O @ Wo + bo -> row-major d_out.
__global__ __launch_bounds__(256) void out_proj(
    const float* __restrict__ Od, const float* __restrict__ Wo,
    const float* __restrict__ bo, float* __restrict__ out)
{
    const int t = threadIdx.x;
    const int c0 = (t & 63) * 4;
    const int r0 = blockIdx.x * 16 + (t >> 6) * 4;

    float acc[4][4];
    {
        float4 bb = *(const float4*)(bo + c0);
        #pragma unroll
        for (int i = 0; i < 4; ++i) {
            acc[i][0] = bb.x; acc[i][1] = bb.y; acc[i][2] = bb.z; acc[i][3] = bb.w;
        }
    }
    for (int k4 = 0; k4 < DIN; k4 += 4) {
        const int h = k4 >> 5, dd = k4 & 31;
        float4 xr[4];
        #pragma unroll
        for (int i = 0; i < 4; ++i) {
            const int row = r0 + i, b = row >> 11, q = row & (Ln - 1);
            xr[i] = *(const float4*)(Od + (((size_t)(b * Hn + h)) * Ln + q) * DEPTH + dd);
        }
        #pragma unroll
        for (int kk = 0; kk < 4; ++kk) {
            float4 w = *(const float4*)(Wo + (size_t)(k4 + kk) * DIN + c0);
            #pragma unroll
            for (int i = 0; i < 4; ++i) {
                float xv = ((const float*)&xr[i])[kk];
                acc[i][0] = fmaf(xv, w.x, acc[i][0]);
                acc[i][1] = fmaf(xv, w.y, acc[i][1]);
                acc[i][2] = fmaf(xv, w.z, acc[i][2]);
                acc[i][3] = fmaf(xv, w.w, acc[i][3]);
            }
        }
    }
    #pragma unroll
    for (int i = 0; i < 4; ++i)
        *(float4*)(out + (size_t)(r0 + i) * DIN + c0) =
            make_float4(acc[i][0], acc[i][1], acc[i][2], acc[i][3]);
}

// ===========================================================================
// FALLBACK PATH (proven in R4): fused kernel, zero workspace
// ===========================================================================
#define QT 128
#define KT 32
#define NKT (Ln / KT)
#define TS 34
#define SST (KT + 1)

__global__ __launch_bounds__(512) void fb_fused_attn(
    const float* __restrict__ Xq, const float* __restrict__ Xk,
    const float* __restrict__ Xv, const int* __restrict__ mask,
    const float* __restrict__ Wq, const float* __restrict__ bq,
    const float* __restrict__ Wk, const float* __restrict__ bk,
    const float* __restrict__ Wv, const float* __restrict__ bv,
    float* __restrict__ out)
{
    __shared__ float Qs[QT * TS];
    __shared__ float Ks[KT * TS];
    __shared__ float Vs[KT * TS];
    __shared__ float Ss[QT * SST];
    __shared__ float mrow[QT], lrow[QT], arow[QT];
    __shared__ int mk[KT];

    const int t = threadIdx.x;
    const int d = t & 31;
    const int rg = t >> 5;
    const int q0 = blockIdx.x * QT;
    const int h = blockIdx.y;
    const int b = blockIdx.z;
    const int hc = h * DEPTH + d;

    {
        const float bqv = bq[hc];
        for (int i = 0; i < 8; ++i) {
            const int r = rg + 16 * i;
            const float* x = Xq + ((size_t)(b * Ln + q0 + r)) * DIN;
            float acc = bqv;
            #pragma unroll 8
            for (int k = 0; k < DIN; ++k) acc = fmaf(x[k], Wq[k * DIN + hc], acc);
            Qs[r * TS + d] = acc * SCALE;
        }
    }
    if (t < QT) { mrow[t] = -INFINITY; lrow[t] = 0.f; }
    float o_acc[8];
    #pragma unroll
    for (int i = 0; i < 8; ++i) o_acc[i] = 0.f;

    const float bkv = bk[hc], bvv = bv[hc];

    for (int kt = 0; kt < NKT; ++kt) {
        const int k0 = kt * KT;
        #pragma unroll
        for (int i = 0; i < 2; ++i) {
            const int r = rg + 16 * i;
            const float* xk = Xk + ((size_t)(b * Ln + k0 + r)) * DIN;
            const float* xv = Xv + ((size_t)(b * Ln + k0 + r)) * DIN;
            float aK = bkv, aV = bvv;
            #pragma unroll 4
            for (int k = 0; k < DIN; ++k) {
                aK = fmaf(xk[k], Wk[k * DIN + hc], aK);
                aV = fmaf(xv[k], Wv[k * DIN + hc], aV);
            }
            Ks[r * TS + d] = aK;
            Vs[r * TS + d] = aV;
        }
        if (t < KT) mk[t] = mask[b * Ln + k0 + t];
        __syncthreads();

        for (int idx = t; idx < QT * KT; idx += 512) {
            const int r = idx >> 5, k = idx & (KT - 1);
            const float2* qv = (const float2*)(Qs + r * TS);
            const float2* kv = (const float2*)(Ks + k * TS);
            float s = 0.f;
            #pragma unroll
            for (int j = 0; j < 16; ++j) {
                float2 a = qv[j], c = kv[j];
                s += a.x * c.x + a.y * c.y;
            }
            Ss[r * SST + k] = mk[k] ? s : NEGC;
        }
        __syncthreads();

        if (t < QT) {
            float tm = -INFINITY;
            #pragma unroll 8
            for (int k = 0; k < KT; ++k) tm = fmaxf(tm, Ss[t * SST + k]);
            const float nm = fmaxf(mrow[t], tm);
            arow[t] = __expf(mrow[t] - nm);
            mrow[t] = nm;
        }
        __syncthreads();

        for (int idx = t; idx < QT * KT; idx += 512) {
            const int r = idx >> 5, k = idx & (KT - 1);
            Ss[r * SST + k] = __expf(Ss[r * SST + k] - mrow[r]);
        }
        __syncthreads();

        if (t < QT) {
            float rs = 0.f;
            #pragma unroll 8
            for (int k = 0; k < KT; ++k) rs += Ss[t * SST + k];
            lrow[t] = arow[t] * lrow[t] + rs;
        }
        #pragma unroll
        for (int i = 0; i < 8; ++i) {
            const int r = rg + 16 * i;
            const float a = arow[r];
            float acc = o_acc[i] * a;
            const float* pr = Ss + r * SST;
            const float* vc = Vs + d;
            #pragma unroll 8
            for (int k = 0; k < KT; ++k) acc = fmaf(pr[k], vc[k * TS], acc);
            o_acc[i] = acc;
        }
        __syncthreads();
    }
    #pragma unroll
    for (int i = 0; i < 8; ++i) {
        const int r = rg + 16 * i;
        out[((size_t)(b * Ln + q0 + r)) * DIN + hc] = o_acc[i] / lrow[r];
    }
}

__global__ __launch_bounds__(256) void fb_out_proj(
    const float* __restrict__ Wo, const float* __restrict__ bo,
    float* __restrict__ out)
{
    __shared__ float xr[4][DIN];
    const int col = threadIdx.x;
    const int r0 = blockIdx.x * 4;
    #pragma unroll
    for (int rr = 0; rr < 4; ++rr)
        xr[rr][col] = out[(size_t)(r0 + rr) * DIN + col];
    __syncthreads();
    const float bb = bo[col];
    float a0 = bb, a1 = bb, a2 = bb, a3 = bb;
    #pragma unroll 4
    for (int k = 0; k < DIN; ++k) {
        const float w = Wo[k * DIN + col];
        a0 = fmaf(xr[0][k], w, a0);
        a1 = fmaf(xr[1][k], w, a1);
        a2 = fmaf(xr[2][k], w, a2);
        a3 = fmaf(xr[3][k], w, a3);
    }
    float* o = out + (size_t)r0 * DIN + col;
    o[0] = a0; o[DIN] = a1; o[2 * DIN] = a2; o[3 * DIN] = a3;
}

// ===========================================================================
extern "C" void kernel_launch(void* const* d_in, const int* in_sizes, int n_in,
                              void* d_out, int out_size, void* d_ws, size_t ws_size,
                              hipStream_t stream) {
    const float* Xq = (const float*)d_in[0];
    const float* Xk = (const float*)d_in[1];
    const float* Xv = (const float*)d_in[2];
    const int* mask = (const int*)d_in[3];
    const float* Wq = (const float*)d_in[4];
    const float* bq = (const float*)d_in[5];
    const float* Wk = (const float*)d_in[6];
    const float* bk = (const float*)d_in[7];
    const float* Wv = (const float*)d_in[8];
    const float* bv = (const float*)d_in[9];
    const float* Wo = (const float*)d_in[10];
    const float* bo = (const float*)d_in[11];
    float* out = (float*)d_out;

    const size_t SZ = (size_t)MR * DIN;          // 1M elements per array
    if (ws_size >= 3 * SZ * sizeof(float)) {
        float* Qd = (float*)d_ws;                // becomes O after flash_attn
        float* Kd = Qd + SZ;
        float* Vd = Kd + SZ;
        qkv_proj<<<dim3(MR / 16, 3), 256, 0, stream>>>(
            Xq, Xk, Xv, Wq, bq, Wk, bk, Wv, bv, Qd, Kd, Vd);
        flash_attn<<<dim3(Ln / 64, Hn, Bn), 256, 0, stream>>>(Qd, Kd, Vd, mask, Qd);
        out_proj<<<MR / 16, 256, 0, stream>>>(Qd, Wo, bo, out);
    } else {
        fb_fused_attn<<<dim3(Ln / QT, Hn, Bn), 512, 0, stream>>>(
            Xq, Xk, Xv, mask, Wq, bq, Wk, bk, Wv, bv, out);
        fb_out_proj<<<MR / 4, 256, 0, stream>>>(Wo, bo, out);
    }
}

// Round 6
// 167.286 us; speedup vs baseline: 16.1051x; 2.5045x over previous
//
#include <hip/hip_runtime.h>

#define Bn 2
#define Ln 2048
#define DIN 256
#define Hn 8
#define DEPTH 32
#define SCALE 0.17677669529663687f      // 1/sqrt(32)
#define NEGC (-4294967296.0f)           // float32(-2^32+1)

typedef _Float16 f16;
typedef _Float16 h8 __attribute__((ext_vector_type(8)));   // A/B frag: 8 f16 = 4 VGPR
typedef float f4 __attribute__((ext_vector_type(4)));      // C/D frag: 4 f32

// ===========================================================================
// FAST PATH: MFMA pipeline. Fragment layouts (verified m89/m91/m120):
//   A[m = lane&15][k = (lane>>4)*8 + j]   (j = 0..7, contiguous in frag)
//   B[n = lane&15][k = (lane>>4)*8 + j]
//   D[row m = (lane>>4)*4 + reg][col n = lane&15]
// ===========================================================================

// ---- Kernel 0: weights -> fp16, transposed to [n][k] (B-frag = 16B load) --
__global__ __launch_bounds__(256) void wt_kernel(
    const float* __restrict__ Wq, const float* __restrict__ Wk,
    const float* __restrict__ Wv, const float* __restrict__ Wo,
    f16* __restrict__ Wt)
{
    const int p = blockIdx.x;
    const float* W = p == 0 ? Wq : p == 1 ? Wk : p == 2 ? Wv : Wo;
    f16* D = Wt + (size_t)p * DIN * DIN;
    const int n = threadIdx.x;
    for (int k = 0; k < DIN; ++k)               // reads coalesced across threads
        D[n * DIN + k] = (f16)W[k * DIN + n];
}

// ---- Kernel 1: QKV projection GEMM. Block 64m x 64n, wave = 16m strip. ----
// Q (pre-scaled by 1/sqrt(32)) and K stored head-major [b,h,L,32];
// V stored TRANSPOSED [b,h,32,L] so flash PV B-frags are contiguous.
__global__ __launch_bounds__(256) void proj_gemm(
    const float* __restrict__ Xq, const float* __restrict__ Xk, const float* __restrict__ Xv,
    const f16* __restrict__ Wt,
    const float* __restrict__ bq, const float* __restrict__ bk, const float* __restrict__ bv,
    f16* __restrict__ Qb, f16* __restrict__ Kb, f16* __restrict__ Vt)
{
    const int p = blockIdx.z;
    const float* X = p == 0 ? Xq : p == 1 ? Xk : Xv;
    const float* bias = p == 0 ? bq : p == 1 ? bk : bv;
    const f16* Wp = Wt + (size_t)p * DIN * DIN;

    const int t = threadIdx.x, w = t >> 6, lane = t & 63;
    const int l15 = lane & 15, quad = lane >> 4;
    const int m0 = blockIdx.x * 64 + w * 16;
    const int n0 = blockIdx.y * 64;

    const float* Arow = X + (size_t)(m0 + l15) * DIN;

    f4 acc[4] = {{0.f,0.f,0.f,0.f},{0.f,0.f,0.f,0.f},{0.f,0.f,0.f,0.f},{0.f,0.f,0.f,0.f}};
    for (int k0 = 0; k0 < DIN; k0 += 32) {
        float4 xa = *(const float4*)(Arow + k0 + quad * 8);
        float4 xb = *(const float4*)(Arow + k0 + quad * 8 + 4);
        h8 af = { (f16)xa.x, (f16)xa.y, (f16)xa.z, (f16)xa.w,
                  (f16)xb.x, (f16)xb.y, (f16)xb.z, (f16)xb.w };
        #pragma unroll
        for (int tt = 0; tt < 4; ++tt) {
            h8 bf = *(const h8*)(Wp + (size_t)(n0 + tt * 16 + l15) * DIN + k0 + quad * 8);
            acc[tt] = __builtin_amdgcn_mfma_f32_16x16x32_f16(af, bf, acc[tt], 0, 0, 0);
        }
    }
    #pragma unroll
    for (int tt = 0; tt < 4; ++tt) {
        const int c = n0 + tt * 16 + l15;            // d_model column (16-tile never straddles a head)
        const float bb = bias[c];
        const int h = c >> 5, dd = c & 31;
        #pragma unroll
        for (int r = 0; r < 4; ++r) {
            const int row = m0 + quad * 4 + r;
            const int b = row >> 11, l = row & (Ln - 1);
            const float v = acc[tt][r] + bb;
            if (p == 0)
                Qb[(((size_t)(b * Hn + h)) * Ln + l) * DEPTH + dd] = (f16)(v * SCALE);
            else if (p == 1)
                Kb[(((size_t)(b * Hn + h)) * Ln + l) * DEPTH + dd] = (f16)v;
            else
                Vt[(((size_t)(b * Hn + h)) * DEPTH + dd) * Ln + l] = (f16)v;
        }
    }
}

// ---- Kernel 2: MFMA flash attention. 4 waves, wave owns 16 q-rows. -------
// No __syncthreads: each wave's P strip in LDS is private. O overwrites Qb.
__global__ __launch_bounds__(256) void flash_mfma(
    const f16* __restrict__ Qb, const f16* __restrict__ Kb,
    const f16* __restrict__ Vt, const int* __restrict__ mask,
    f16* __restrict__ Ob)
{
    __shared__ f16 Ps[4][16][72];    // stride 72: 16B-aligned rows, <=2-way banks
    const int t = threadIdx.x, w = t >> 6, lane = t & 63;
    const int l15 = lane & 15, quad = lane >> 4;
    const int b = blockIdx.z, h = blockIdx.y;
    const int q0 = blockIdx.x * 64 + w * 16;
    const size_t hb = (size_t)(b * Hn + h);
    const f16* Qh = Qb + hb * Ln * DEPTH;
    const f16* Kh = Kb + hb * Ln * DEPTH;
    const f16* Vh = Vt + hb * DEPTH * Ln;
    const int* mrow = mask + b * Ln;

    const h8 qf = *(const h8*)(Qh + (size_t)(q0 + l15) * DEPTH + quad * 8);  // A-frag, loaded once

    f4 o0 = {0.f,0.f,0.f,0.f}, o1 = {0.f,0.f,0.f,0.f};
    float m_run[4] = {-INFINITY, -INFINITY, -INFINITY, -INFINITY};
    float l_run[4] = {0.f, 0.f, 0.f, 0.f};

    for (int kt = 0; kt < Ln / 64; ++kt) {
        const int k0 = kt * 64;
        // ---- S = Q.K^T : 4 n-tiles of 16 keys, one K=32 MFMA each ----
        f4 s[4];
        int mk[4];
        #pragma unroll
        for (int tt = 0; tt < 4; ++tt) {
            const int key = k0 + tt * 16 + l15;
            h8 kf = *(const h8*)(Kh + (size_t)key * DEPTH + quad * 8);  // B-frag
            f4 z = {0.f, 0.f, 0.f, 0.f};
            s[tt] = __builtin_amdgcn_mfma_f32_16x16x32_f16(qf, kf, z, 0, 0, 0);
            mk[tt] = mrow[key];
        }
        // ---- mask + row max (C-layout row = quad*4+r matches stats layout) ----
        float rmax[4] = {-INFINITY, -INFINITY, -INFINITY, -INFINITY};
        #pragma unroll
        for (int tt = 0; tt < 4; ++tt)
            #pragma unroll
            for (int r = 0; r < 4; ++r) {
                const float v = mk[tt] ? s[tt][r] : NEGC;
                s[tt][r] = v;
                rmax[r] = fmaxf(rmax[r], v);
            }
        #pragma unroll
        for (int r = 0; r < 4; ++r)
            #pragma unroll
            for (int off = 1; off < 16; off <<= 1)
                rmax[r] = fmaxf(rmax[r], __shfl_xor(rmax[r], off, 64));

        float alpha[4], rsum[4];
        #pragma unroll
        for (int r = 0; r < 4; ++r) {
            const float mn = fmaxf(m_run[r], rmax[r]);
            alpha[r] = __expf(m_run[r] - mn);     // first tile: exp(-inf)=0
            m_run[r] = mn;
            rsum[r] = 0.f;
        }
        // ---- P = exp(S-m) -> LDS (A-layout source for PV), row sums ----
        #pragma unroll
        for (int tt = 0; tt < 4; ++tt)
            #pragma unroll
            for (int r = 0; r < 4; ++r) {
                const float pv = __expf(s[tt][r] - m_run[r]);
                Ps[w][quad * 4 + r][tt * 16 + l15] = (f16)pv;
                rsum[r] += pv;
            }
        #pragma unroll
        for (int r = 0; r < 4; ++r) {
            #pragma unroll
            for (int off = 1; off < 16; off <<= 1)
                rsum[r] += __shfl_xor(rsum[r], off, 64);
            l_run[r] = alpha[r] * l_run[r] + rsum[r];
        }
        // ---- O = alpha*O + P.V ----
        #pragma unroll
        for (int r = 0; r < 4; ++r) { o0[r] *= alpha[r]; o1[r] *= alpha[r]; }
        #pragma unroll
        for (int ks = 0; ks < 2; ++ks) {
            h8 pf = *(const h8*)(&Ps[w][l15][ks * 32 + quad * 8]);               // A-frag
            h8 v0 = *(const h8*)(Vh + (size_t)l15 * Ln        + k0 + ks * 32 + quad * 8);
            h8 v1 = *(const h8*)(Vh + (size_t)(16 + l15) * Ln + k0 + ks * 32 + quad * 8);
            o0 = __builtin_amdgcn_mfma_f32_16x16x32_f16(pf, v0, o0, 0, 0, 0);
            o1 = __builtin_amdgcn_mfma_f32_16x16x32_f16(pf, v1, o1, 0, 0, 0);
        }
    }
    // ---- epilogue: normalize, write head-major (over Q buffer, own rows) ----
    f16* Orow = Ob + hb * Ln * DEPTH;
    #pragma unroll
    for (int r = 0; r < 4; ++r) {
        const float inv = 1.0f / l_run[r];
        const int q = q0 + quad * 4 + r;
        Orow[(size_t)q * DEPTH + l15]      = (f16)(o0[r] * inv);
        Orow[(size_t)q * DEPTH + 16 + l15] = (f16)(o1[r] * inv);
    }
}

// ---- Kernel 3: output projection GEMM, head-major O @ Wo^T + bo -> fp32 ---
__global__ __launch_bounds__(256) void out_gemm(
    const f16* __restrict__ Ob, const f16* __restrict__ Wt,
    const float* __restrict__ bo, float* __restrict__ out)
{
    const f16* Wp = Wt + (size_t)3 * DIN * DIN;
    const int t = threadIdx.x, w = t >> 6, lane = t & 63;
    const int l15 = lane & 15, quad = lane >> 4;
    const int m0 = blockIdx.x * 64 + w * 16;
    const int n0 = blockIdx.y * 64;
    const int rA = m0 + l15, bA = rA >> 11, qA = rA & (Ln - 1);

    f4 acc[4] = {{0.f,0.f,0.f,0.f},{0.f,0.f,0.f,0.f},{0.f,0.f,0.f,0.f},{0.f,0.f,0.f,0.f}};
    for (int k0 = 0; k0 < DIN; k0 += 32) {
        const int h = k0 >> 5;                    // frag stays inside one head
        h8 af = *(const h8*)(Ob + (((size_t)(bA * Hn + h)) * Ln + qA) * DEPTH + quad * 8);
        #pragma unroll
        for (int tt = 0; tt < 4; ++tt) {
            h8 bf = *(const h8*)(Wp + (size_t)(n0 + tt * 16 + l15) * DIN + k0 + quad * 8);
            acc[tt] = __builtin_amdgcn_mfma_f32_16x16x32_f16(af, bf, acc[tt], 0, 0, 0);
        }
    }
    #pragma unroll
    for (int tt = 0; tt < 4; ++tt) {
        const int c = n0 + tt * 16 + l15;
        const float bb = bo[c];
        #pragma unroll
        for (int r = 0; r < 4; ++r)
            out[(size_t)(m0 + quad * 4 + r) * DIN + c] = acc[tt][r] + bb;
    }
}

// ===========================================================================
// FALLBACK PATH (proven R4): fused kernel, zero workspace
// ===========================================================================
#define QT 128
#define KT 32
#define TS 34
#define SST (KT + 1)

__global__ __launch_bounds__(512) void fb_fused_attn(
    const float* __restrict__ Xq, const float* __restrict__ Xk,
    const float* __restrict__ Xv, const int* __restrict__ mask,
    const float* __restrict__ Wq, const float* __restrict__ bq,
    const float* __restrict__ Wk, const float* __restrict__ bk,
    const float* __restrict__ Wv, const float* __restrict__ bv,
    float* __restrict__ out)
{
    __shared__ float Qs[QT * TS];
    __shared__ float Ks[KT * TS];
    __shared__ float Vs[KT * TS];
    __shared__ float Ss[QT * SST];
    __shared__ float mrow[QT], lrow[QT], arow[QT];
    __shared__ int mk[KT];

    const int t = threadIdx.x;
    const int d = t & 31;
    const int rg = t >> 5;
    const int q0 = blockIdx.x * QT;
    const int h = blockIdx.y;
    const int b = blockIdx.z;
    const int hc = h * DEPTH + d;

    {
        const float bqv = bq[hc];
        for (int i = 0; i < 8; ++i) {
            const int r = rg + 16 * i;
            const float* x = Xq + ((size_t)(b * Ln + q0 + r)) * DIN;
            float acc = bqv;
            #pragma unroll 8
            for (int k = 0; k < DIN; ++k) acc = fmaf(x[k], Wq[k * DIN + hc], acc);
            Qs[r * TS + d] = acc * SCALE;
        }
    }
    if (t < QT) { mrow[t] = -INFINITY; lrow[t] = 0.f; }
    float o_acc[8];
    #pragma unroll
    for (int i = 0; i < 8; ++i) o_acc[i] = 0.f;

    const float bkv = bk[hc], bvv = bv[hc];

    for (int kt = 0; kt < Ln / KT; ++kt) {
        const int k0 = kt * KT;
        #pragma unroll
        for (int i = 0; i < 2; ++i) {
            const int r = rg + 16 * i;
            const float* xk = Xk + ((size_t)(b * Ln + k0 + r)) * DIN;
            const float* xv = Xv + ((size_t)(b * Ln + k0 + r)) * DIN;
            float aK = bkv, aV = bvv;
            #pragma unroll 4
            for (int k = 0; k < DIN; ++k) {
                aK = fmaf(xk[k], Wk[k * DIN + hc], aK);
                aV = fmaf(xv[k], Wv[k * DIN + hc], aV);
            }
            Ks[r * TS + d] = aK;
            Vs[r * TS + d] = aV;
        }
        if (t < KT) mk[t] = mask[b * Ln + k0 + t];
        __syncthreads();

        for (int idx = t; idx < QT * KT; idx += 512) {
            const int r = idx >> 5, k = idx & (KT - 1);
            const float2* qv = (const float2*)(Qs + r * TS);
            const float2* kv = (const float2*)(Ks + k * TS);
            float s = 0.f;
            #pragma unroll
            for (int j = 0; j < 16; ++j) {
                float2 a = qv[j], c = kv[j];
                s += a.x * c.x + a.y * c.y;
            }
            Ss[r * SST + k] = mk[k] ? s : NEGC;
        }
        __syncthreads();

        if (t < QT) {
            float tm = -INFINITY;
            #pragma unroll 8
            for (int k = 0; k < KT; ++k) tm = fmaxf(tm, Ss[t * SST + k]);
            const float nm = fmaxf(mrow[t], tm);
            arow[t] = __expf(mrow[t] - nm);
            mrow[t] = nm;
        }
        __syncthreads();

        for (int idx = t; idx < QT * KT; idx += 512) {
            const int r = idx >> 5, k = idx & (KT - 1);
            Ss[r * SST + k] = __expf(Ss[r * SST + k] - mrow[r]);
        }
        __syncthreads();

        if (t < QT) {
            float rs = 0.f;
            #pragma unroll 8
            for (int k = 0; k < KT; ++k) rs += Ss[t * SST + k];
            lrow[t] = arow[t] * lrow[t] + rs;
        }
        #pragma unroll
        for (int i = 0; i < 8; ++i) {
            const int r = rg + 16 * i;
            const float a = arow[r];
            float acc = o_acc[i] * a;
            const float* pr = Ss + r * SST;
            const float* vc = Vs + d;
            #pragma unroll 8
            for (int k = 0; k < KT; ++k) acc = fmaf(pr[k], vc[k * TS], acc);
            o_acc[i] = acc;
        }
        __syncthreads();
    }
    #pragma unroll
    for (int i = 0; i < 8; ++i) {
        const int r = rg + 16 * i;
        out[((size_t)(b * Ln + q0 + r)) * DIN + hc] = o_acc[i] / lrow[r];
    }
}

__global__ __launch_bounds__(256) void fb_out_proj(
    const float* __restrict__ Wo, const float* __restrict__ bo,
    float* __restrict__ out)
{
    __shared__ float xr[4][DIN];
    const int col = threadIdx.x;
    const int r0 = blockIdx.x * 4;
    #pragma unroll
    for (int rr = 0; rr < 4; ++rr)
        xr[rr][col] = out[(size_t)(r0 + rr) * DIN + col];
    __syncthreads();
    const float bb = bo[col];
    float a0 = bb, a1 = bb, a2 = bb, a3 = bb;
    #pragma unroll 4
    for (int k = 0; k < DIN; ++k) {
        const float w = Wo[k * DIN + col];
        a0 = fmaf(xr[0][k], w, a0);
        a1 = fmaf(xr[1][k], w, a1);
        a2 = fmaf(xr[2][k], w, a2);
        a3 = fmaf(xr[3][k], w, a3);
    }
    float* o = out + (size_t)r0 * DIN + col;
    o[0] = a0; o[DIN] = a1; o[2 * DIN] = a2; o[3 * DIN] = a3;
}

// ===========================================================================
extern "C" void kernel_launch(void* const* d_in, const int* in_sizes, int n_in,
                              void* d_out, int out_size, void* d_ws, size_t ws_size,
                              hipStream_t stream) {
    const float* Xq = (const float*)d_in[0];
    const float* Xk = (const float*)d_in[1];
    const float* Xv = (const float*)d_in[2];
    const int* mask = (const int*)d_in[3];
    const float* Wq = (const float*)d_in[4];
    const float* bq = (const float*)d_in[5];
    const float* Wk = (const float*)d_in[6];
    const float* bk = (const float*)d_in[7];
    const float* Wv = (const float*)d_in[8];
    const float* bv = (const float*)d_in[9];
    const float* Wo = (const float*)d_in[10];
    const float* bo = (const float*)d_in[11];
    float* out = (float*)d_out;

    const size_t WT_E = (size_t)4 * DIN * DIN;            // 256 KiB*2 of f16
    const size_t HB_E = (size_t)Bn * Hn * Ln * DEPTH;     // 1M f16 each
    const size_t need = (WT_E + 3 * HB_E) * sizeof(f16);  // ~6.8 MB

    if (ws_size >= need) {
        f16* Wt = (f16*)d_ws;
        f16* Qb = Wt + WT_E;     // becomes O after flash_mfma
        f16* Kb = Qb + HB_E;
        f16* Vt = Kb + HB_E;
        wt_kernel<<<4, 256, 0, stream>>>(Wq, Wk, Wv, Wo, Wt);
        proj_gemm<<<dim3(Bn * Ln / 64, DIN / 64, 3), 256, 0, stream>>>(
            Xq, Xk, Xv, Wt, bq, bk, bv, Qb, Kb, Vt);
        flash_mfma<<<dim3(Ln / 64, Hn, Bn), 256, 0, stream>>>(Qb, Kb, Vt, mask, Qb);
        out_gemm<<<dim3(Bn * Ln / 64, DIN / 64), 256, 0, stream>>>(Qb, Wt, bo, out);
    } else {
        fb_fused_attn<<<dim3(Ln / QT, Hn, Bn), 512, 0, stream>>>(
            Xq, Xk, Xv, mask, Wq, bq, Wk, bk, Wv, bv, out);
        fb_out_proj<<<Bn * Ln / 4, 256, 0, stream>>>(Wo, bo, out);
    }
}

// Round 7
// 160.549 us; speedup vs baseline: 16.7809x; 1.0420x over previous
//
#include <hip/hip_runtime.h>

#define Bn 2
#define Ln 2048
#define DIN 256
#define Hn 8
#define DEPTH 32
#define SCALE 0.17677669529663687f      // 1/sqrt(32)
#define NEGC (-4294967296.0f)           // float32(-2^32+1)

typedef _Float16 f16;
typedef _Float16 h8 __attribute__((ext_vector_type(8)));   // A/B frag: 8 f16 = 4 VGPR
typedef _Float16 h4 __attribute__((ext_vector_type(4)));   // packed 8B store
typedef float f4 __attribute__((ext_vector_type(4)));      // C/D frag: 4 f32

// ===========================================================================
// MFMA pipeline. Fragment layouts (verified m89/m91/m120):
//   A[m = lane&15][k = (lane>>4)*8 + j]
//   B[n = lane&15][k = (lane>>4)*8 + j]
//   D[row m = (lane>>4)*4 + reg][col n = lane&15]
// flash computes S^T (A=K, B=Q) so softmax stats are per-lane scalars.
// ===========================================================================

// ---- Kernel 0: weights -> fp16 transposed [n][k], LDS-tiled. Grid (4,16). --
__global__ __launch_bounds__(256) void wt_kernel(
    const float* __restrict__ Wq, const float* __restrict__ Wk,
    const float* __restrict__ Wv, const float* __restrict__ Wo,
    f16* __restrict__ Wt)
{
    __shared__ float tileS[64][65];
    const int p = blockIdx.x;
    const float* W = p == 0 ? Wq : p == 1 ? Wk : p == 2 ? Wv : Wo;
    f16* D = Wt + (size_t)p * DIN * DIN;
    const int t = threadIdx.x;
    const int tk = (blockIdx.y & 3) * 64, tn = (blockIdx.y >> 2) * 64;
    #pragma unroll
    for (int i = 0; i < 16; ++i) {
        const int row = i * 4 + (t >> 6), col = t & 63;          // (k, n) local
        tileS[row][col] = W[(size_t)(tk + row) * DIN + tn + col]; // coalesced 256B
    }
    __syncthreads();
    #pragma unroll
    for (int i = 0; i < 16; ++i) {
        const int ln = i * 4 + (t >> 6), lk = t & 63;
        D[(size_t)(tn + ln) * DIN + tk + lk] = (f16)tileS[lk][ln]; // coalesced 128B
    }
}

// ---- Kernel 1: QKV projection GEMM. Block 64m x 64n, wave = 16m strip. ----
// Q (pre-scaled) and K head-major [b,h,L,32]; V TRANSPOSED [b,h,32,L].
__global__ __launch_bounds__(256) void proj_gemm(
    const float* __restrict__ Xq, const float* __restrict__ Xk, const float* __restrict__ Xv,
    const f16* __restrict__ Wt,
    const float* __restrict__ bq, const float* __restrict__ bk, const float* __restrict__ bv,
    f16* __restrict__ Qb, f16* __restrict__ Kb, f16* __restrict__ Vt)
{
    const int p = blockIdx.z;
    const float* X = p == 0 ? Xq : p == 1 ? Xk : Xv;
    const float* bias = p == 0 ? bq : p == 1 ? bk : bv;
    const f16* Wp = Wt + (size_t)p * DIN * DIN;

    const int t = threadIdx.x, w = t >> 6, lane = t & 63;
    const int l15 = lane & 15, quad = lane >> 4;
    const int m0 = blockIdx.x * 64 + w * 16;
    const int n0 = blockIdx.y * 64;

    const float* Arow = X + (size_t)(m0 + l15) * DIN;

    f4 acc[4] = {{0.f,0.f,0.f,0.f},{0.f,0.f,0.f,0.f},{0.f,0.f,0.f,0.f},{0.f,0.f,0.f,0.f}};
    for (int k0 = 0; k0 < DIN; k0 += 32) {
        float4 xa = *(const float4*)(Arow + k0 + quad * 8);
        float4 xb = *(const float4*)(Arow + k0 + quad * 8 + 4);
        h8 af = { (f16)xa.x, (f16)xa.y, (f16)xa.z, (f16)xa.w,
                  (f16)xb.x, (f16)xb.y, (f16)xb.z, (f16)xb.w };
        #pragma unroll
        for (int tt = 0; tt < 4; ++tt) {
            h8 bf = *(const h8*)(Wp + (size_t)(n0 + tt * 16 + l15) * DIN + k0 + quad * 8);
            acc[tt] = __builtin_amdgcn_mfma_f32_16x16x32_f16(af, bf, acc[tt], 0, 0, 0);
        }
    }
    #pragma unroll
    for (int tt = 0; tt < 4; ++tt) {
        const int c = n0 + tt * 16 + l15;            // 16-tile never straddles a head
        const float bb = bias[c];
        const int h = c >> 5, dd = c & 31;
        #pragma unroll
        for (int r = 0; r < 4; ++r) {
            const int row = m0 + quad * 4 + r;
            const int b = row >> 11, l = row & (Ln - 1);
            const float v = acc[tt][r] + bb;
            if (p == 0)
                Qb[(((size_t)(b * Hn + h)) * Ln + l) * DEPTH + dd] = (f16)(v * SCALE);
            else if (p == 1)
                Kb[(((size_t)(b * Hn + h)) * Ln + l) * DEPTH + dd] = (f16)v;
            else
                Vt[(((size_t)(b * Hn + h)) * DEPTH + dd) * Ln + l] = (f16)v;
        }
    }
}

// ---- Kernel 2: MFMA flash attention, transposed scores. ------------------
// Grid (hb=16, qtile=32): lid%8 = hb%8 -> all q-blocks of one (b,h) on one XCD.
// 4 waves, wave owns 16 q. Stats per-lane scalars (q = lane&15). No barriers.
__global__ __launch_bounds__(256) void flash_mfma(
    const f16* __restrict__ Qb, const f16* __restrict__ Kb,
    const f16* __restrict__ Vt, const int* __restrict__ mask,
    f16* __restrict__ Ob)
{
    __shared__ f16 Ps[4][16 * 72];   // wave-private strip [q][key], stride 72
    const int t = threadIdx.x, w = t >> 6, lane = t & 63;
    const int l15 = lane & 15, quad = lane >> 4;
    const int hb = blockIdx.x;                 // h = hb&7, b = hb>>3
    const int q0 = blockIdx.y * 64 + w * 16;
    const int b = hb >> 3;
    const f16* Qh = Qb + (size_t)hb * Ln * DEPTH;
    const f16* Kh = Kb + (size_t)hb * Ln * DEPTH;
    const f16* Vh = Vt + (size_t)hb * DEPTH * Ln;
    const int* mrow = mask + b * Ln;
    f16* Psw = &Ps[w][0];

    const h8 qf = *(const h8*)(Qh + (size_t)(q0 + l15) * DEPTH + quad * 8);  // B-frag

    f4 o0 = {0.f,0.f,0.f,0.f}, o1 = {0.f,0.f,0.f,0.f};
    float m_run = -INFINITY, l_run = 0.f;      // per-lane: q = q0 + l15

    for (int kt = 0; kt < Ln / 64; ++kt) {
        const int k0 = kt * 64;
        // ---- S^T = K.Q^T : lane holds 16 keys of column q=l15 ----
        f4 s[4];
        int4 mk4[4];
        #pragma unroll
        for (int tt = 0; tt < 4; ++tt) {
            h8 kf = *(const h8*)(Kh + (size_t)(k0 + tt * 16 + l15) * DEPTH + quad * 8);
            f4 z = {0.f, 0.f, 0.f, 0.f};
            s[tt] = __builtin_amdgcn_mfma_f32_16x16x32_f16(kf, qf, z, 0, 0, 0);
            mk4[tt] = *(const int4*)(mrow + k0 + tt * 16 + quad * 4);
        }
        // ---- mask + in-register row max, then 2-shuffle cross-quad reduce ----
        float rmax = -INFINITY;
        #pragma unroll
        for (int tt = 0; tt < 4; ++tt) {
            const int* mkp = (const int*)&mk4[tt];
            #pragma unroll
            for (int r = 0; r < 4; ++r) {
                const float v = mkp[r] ? s[tt][r] : NEGC;
                s[tt][r] = v;
                rmax = fmaxf(rmax, v);
            }
        }
        rmax = fmaxf(rmax, __shfl_xor(rmax, 16, 64));
        rmax = fmaxf(rmax, __shfl_xor(rmax, 32, 64));

        const float mn = fmaxf(m_run, rmax);
        const float alpha = __expf(m_run - mn);      // first tile: exp(-inf)=0
        m_run = mn;

        // ---- P = exp(S^T - m) -> packed 8B LDS stores; in-register row sum ----
        float rsum = 0.f;
        #pragma unroll
        for (int tt = 0; tt < 4; ++tt) {
            h4 pk;
            #pragma unroll
            for (int r = 0; r < 4; ++r) {
                const float pv = __expf(s[tt][r] - mn);
                rsum += pv;
                pk[r] = (f16)pv;
            }
            *(h4*)(Psw + l15 * 72 + tt * 16 + quad * 4) = pk;   // P[q][key]
        }
        rsum += __shfl_xor(rsum, 16, 64);
        rsum += __shfl_xor(rsum, 32, 64);
        l_run = alpha * l_run + rsum;

        // ---- O^T = V^T.P : A = V^T (contig), B = P[q][key]; alpha per-lane ----
        #pragma unroll
        for (int r = 0; r < 4; ++r) { o0[r] *= alpha; o1[r] *= alpha; }
        #pragma unroll
        for (int ks = 0; ks < 2; ++ks) {
            h8 pf = *(const h8*)(Psw + l15 * 72 + ks * 32 + quad * 8);      // B-frag
            h8 v0 = *(const h8*)(Vh + (size_t)l15 * Ln        + k0 + ks * 32 + quad * 8);
            h8 v1 = *(const h8*)(Vh + (size_t)(16 + l15) * Ln + k0 + ks * 32 + quad * 8);
            o0 = __builtin_amdgcn_mfma_f32_16x16x32_f16(v0, pf, o0, 0, 0, 0);
            o1 = __builtin_amdgcn_mfma_f32_16x16x32_f16(v1, pf, o1, 0, 0, 0);
        }
    }
    // ---- epilogue: O^T[d][q=l15] -> head-major Ob[q][d], packed 8B stores ----
    const float inv = 1.0f / l_run;
    f16* Orow = Ob + ((size_t)hb * Ln + q0 + l15) * DEPTH;
    h4 s0, s1;
    #pragma unroll
    for (int r = 0; r < 4; ++r) {
        s0[r] = (f16)(o0[r] * inv);      // d = quad*4 + r
        s1[r] = (f16)(o1[r] * inv);      // d = 16 + quad*4 + r
    }
    *(h4*)(Orow + quad * 4)      = s0;
    *(h4*)(Orow + 16 + quad * 4) = s1;
}

// ---- Kernel 3: output projection GEMM, head-major O @ Wo^T + bo -> fp32 ---
__global__ __launch_bounds__(256) void out_gemm(
    const f16* __restrict__ Ob, const f16* __restrict__ Wt,
    const float* __restrict__ bo, float* __restrict__ out)
{
    const f16* Wp = Wt + (size_t)3 * DIN * DIN;
    const int t = threadIdx.x, w = t >> 6, lane = t & 63;
    const int l15 = lane & 15, quad = lane >> 4;
    const int m0 = blockIdx.x * 64 + w * 16;
    const int n0 = blockIdx.y * 64;
    const int rA = m0 + l15, bA = rA >> 11, qA = rA & (Ln - 1);

    f4 acc[4] = {{0.f,0.f,0.f,0.f},{0.f,0.f,0.f,0.f},{0.f,0.f,0.f,0.f},{0.f,0.f,0.f,0.f}};
    for (int k0 = 0; k0 < DIN; k0 += 32) {
        const int h = k0 >> 5;                    // frag stays inside one head
        h8 af = *(const h8*)(Ob + (((size_t)(bA * Hn + h)) * Ln + qA) * DEPTH + quad * 8);
        #pragma unroll
        for (int tt = 0; tt < 4; ++tt) {
            h8 bf = *(const h8*)(Wp + (size_t)(n0 + tt * 16 + l15) * DIN + k0 + quad * 8);
            acc[tt] = __builtin_amdgcn_mfma_f32_16x16x32_f16(af, bf, acc[tt], 0, 0, 0);
        }
    }
    #pragma unroll
    for (int tt = 0; tt < 4; ++tt) {
        const int c = n0 + tt * 16 + l15;
        const float bb = bo[c];
        #pragma unroll
        for (int r = 0; r < 4; ++r)
            out[(size_t)(m0 + quad * 4 + r) * DIN + c] = acc[tt][r] + bb;
    }
}

// ===========================================================================
// FALLBACK PATH (proven R4): fused kernel, zero workspace
// ===========================================================================
#define QT 128
#define KT 32
#define TS 34
#define SST (KT + 1)

__global__ __launch_bounds__(512) void fb_fused_attn(
    const float* __restrict__ Xq, const float* __restrict__ Xk,
    const float* __restrict__ Xv, const int* __restrict__ mask,
    const float* __restrict__ Wq, const float* __restrict__ bq,
    const float* __restrict__ Wk, const float* __restrict__ bk,
    const float* __restrict__ Wv, const float* __restrict__ bv,
    float* __restrict__ out)
{
    __shared__ float Qs[QT * TS];
    __shared__ float Ks[KT * TS];
    __shared__ float Vs[KT * TS];
    __shared__ float Ss[QT * SST];
    __shared__ float mrow[QT], lrow[QT], arow[QT];
    __shared__ int mk[KT];

    const int t = threadIdx.x;
    const int d = t & 31;
    const int rg = t >> 5;
    const int q0 = blockIdx.x * QT;
    const int h = blockIdx.y;
    const int b = blockIdx.z;
    const int hc = h * DEPTH + d;

    {
        const float bqv = bq[hc];
        for (int i = 0; i < 8; ++i) {
            const int r = rg + 16 * i;
            const float* x = Xq + ((size_t)(b * Ln + q0 + r)) * DIN;
            float acc = bqv;
            #pragma unroll 8
            for (int k = 0; k < DIN; ++k) acc = fmaf(x[k], Wq[k * DIN + hc], acc);
            Qs[r * TS + d] = acc * SCALE;
        }
    }
    if (t < QT) { mrow[t] = -INFINITY; lrow[t] = 0.f; }
    float o_acc[8];
    #pragma unroll
    for (int i = 0; i < 8; ++i) o_acc[i] = 0.f;

    const float bkv = bk[hc], bvv = bv[hc];

    for (int kt = 0; kt < Ln / KT; ++kt) {
        const int k0 = kt * KT;
        #pragma unroll
        for (int i = 0; i < 2; ++i) {
            const int r = rg + 16 * i;
            const float* xk = Xk + ((size_t)(b * Ln + k0 + r)) * DIN;
            const float* xv = Xv + ((size_t)(b * Ln + k0 + r)) * DIN;
            float aK = bkv, aV = bvv;
            #pragma unroll 4
            for (int k = 0; k < DIN; ++k) {
                aK = fmaf(xk[k], Wk[k * DIN + hc], aK);
                aV = fmaf(xv[k], Wv[k * DIN + hc], aV);
            }
            Ks[r * TS + d] = aK;
            Vs[r * TS + d] = aV;
        }
        if (t < KT) mk[t] = mask[b * Ln + k0 + t];
        __syncthreads();

        for (int idx = t; idx < QT * KT; idx += 512) {
            const int r = idx >> 5, k = idx & (KT - 1);
            const float2* qv = (const float2*)(Qs + r * TS);
            const float2* kv = (const float2*)(Ks + k * TS);
            float s = 0.f;
            #pragma unroll
            for (int j = 0; j < 16; ++j) {
                float2 a = qv[j], c = kv[j];
                s += a.x * c.x + a.y * c.y;
            }
            Ss[r * SST + k] = mk[k] ? s : NEGC;
        }
        __syncthreads();

        if (t < QT) {
            float tm = -INFINITY;
            #pragma unroll 8
            for (int k = 0; k < KT; ++k) tm = fmaxf(tm, Ss[t * SST + k]);
            const float nm = fmaxf(mrow[t], tm);
            arow[t] = __expf(mrow[t] - nm);
            mrow[t] = nm;
        }
        __syncthreads();

        for (int idx = t; idx < QT * KT; idx += 512) {
            const int r = idx >> 5, k = idx & (KT - 1);
            Ss[r * SST + k] = __expf(Ss[r * SST + k] - mrow[r]);
        }
        __syncthreads();

        if (t < QT) {
            float rs = 0.f;
            #pragma unroll 8
            for (int k = 0; k < KT; ++k) rs += Ss[t * SST + k];
            lrow[t] = arow[t] * lrow[t] + rs;
        }
        #pragma unroll
        for (int i = 0; i < 8; ++i) {
            const int r = rg + 16 * i;
            const float a = arow[r];
            float acc = o_acc[i] * a;
            const float* pr = Ss + r * SST;
            const float* vc = Vs + d;
            #pragma unroll 8
            for (int k = 0; k < KT; ++k) acc = fmaf(pr[k], vc[k * TS], acc);
            o_acc[i] = acc;
        }
        __syncthreads();
    }
    #pragma unroll
    for (int i = 0; i < 8; ++i) {
        const int r = rg + 16 * i;
        out[((size_t)(b * Ln + q0 + r)) * DIN + hc] = o_acc[i] / lrow[r];
    }
}

__global__ __launch_bounds__(256) void fb_out_proj(
    const float* __restrict__ Wo, const float* __restrict__ bo,
    float* __restrict__ out)
{
    __shared__ float xr[4][DIN];
    const int col = threadIdx.x;
    const int r0 = blockIdx.x * 4;
    #pragma unroll
    for (int rr = 0; rr < 4; ++rr)
        xr[rr][col] = out[(size_t)(r0 + rr) * DIN + col];
    __syncthreads();
    const float bb = bo[col];
    float a0 = bb, a1 = bb, a2 = bb, a3 = bb;
    #pragma unroll 4
    for (int k = 0; k < DIN; ++k) {
        const float w = Wo[k * DIN + col];
        a0 = fmaf(xr[0][k], w, a0);
        a1 = fmaf(xr[1][k], w, a1);
        a2 = fmaf(xr[2][k], w, a2);
        a3 = fmaf(xr[3][k], w, a3);
    }
    float* o = out + (size_t)r0 * DIN + col;
    o[0] = a0; o[DIN] = a1; o[2 * DIN] = a2; o[3 * DIN] = a3;
}

// ===========================================================================
extern "C" void kernel_launch(void* const* d_in, const int* in_sizes, int n_in,
                              void* d_out, int out_size, void* d_ws, size_t ws_size,
                              hipStream_t stream) {
    const float* Xq = (const float*)d_in[0];
    const float* Xk = (const float*)d_in[1];
    const float* Xv = (const float*)d_in[2];
    const int* mask = (const int*)d_in[3];
    const float* Wq = (const float*)d_in[4];
    const float* bq = (const float*)d_in[5];
    const float* Wk = (const float*)d_in[6];
    const float* bk = (const float*)d_in[7];
    const float* Wv = (const float*)d_in[8];
    const float* bv = (const float*)d_in[9];
    const float* Wo = (const float*)d_in[10];
    const float* bo = (const float*)d_in[11];
    float* out = (float*)d_out;

    const size_t WT_E = (size_t)4 * DIN * DIN;            // 512 KiB of f16
    const size_t HB_E = (size_t)Bn * Hn * Ln * DEPTH;     // 1M f16 each
    const size_t need = (WT_E + 3 * HB_E) * sizeof(f16);  // ~6.8 MB

    if (ws_size >= need) {
        f16* Wt = (f16*)d_ws;
        f16* Qb = Wt + WT_E;     // becomes O after flash_mfma
        f16* Kb = Qb + HB_E;
        f16* Vt = Kb + HB_E;
        wt_kernel<<<dim3(4, 16), 256, 0, stream>>>(Wq, Wk, Wv, Wo, Wt);
        proj_gemm<<<dim3(Bn * Ln / 64, DIN / 64, 3), 256, 0, stream>>>(
            Xq, Xk, Xv, Wt, bq, bk, bv, Qb, Kb, Vt);
        flash_mfma<<<dim3(Bn * Hn, Ln / 64), 256, 0, stream>>>(Qb, Kb, Vt, mask, Qb);
        out_gemm<<<dim3(Bn * Ln / 64, DIN / 64), 256, 0, stream>>>(Qb, Wt, bo, out);
    } else {
        fb_fused_attn<<<dim3(Ln / QT, Hn, Bn), 512, 0, stream>>>(
            Xq, Xk, Xv, mask, Wq, bq, Wk, bk, Wv, bv, out);
        fb_out_proj<<<Bn * Ln / 4, 256, 0, stream>>>(Wo, bo, out);
    }
}

// Round 8
// 150.073 us; speedup vs baseline: 17.9523x; 1.0698x over previous
//
#include <hip/hip_runtime.h>

#define Bn 2
#define Ln 2048
#define DIN 256
#define Hn 8
#define DEPTH 32
#define SCALE 0.17677669529663687f      // 1/sqrt(32)
#define NEGC (-4294967296.0f)           // float32(-2^32+1)

typedef _Float16 f16;
typedef _Float16 h8 __attribute__((ext_vector_type(8)));   // A/B frag: 8 f16 = 4 VGPR
typedef _Float16 h4 __attribute__((ext_vector_type(4)));   // packed 8B store
typedef float f4 __attribute__((ext_vector_type(4)));      // C/D frag: 4 f32

#define WLS 264   // LDS W-tile row stride (f16): 528B = 33*16B aligned, 2-way banks

// ===========================================================================
// MFMA pipeline. Fragment layouts (verified m89/m91/m120):
//   A[m = lane&15][k = (lane>>4)*8 + j]
//   B[n = lane&15][k = (lane>>4)*8 + j]
//   D[row m = (lane>>4)*4 + reg][col n = lane&15]
// flash computes S^T (A=K, B=Q) so softmax stats are per-lane scalars.
// ===========================================================================

// ---- Kernel 1: QKV projection GEMM; W staged fp32->f16 transposed in LDS. --
// Block 64m x 64n, wave = 16m strip. Q (pre-scaled) / K head-major [b,h,L,32];
// V TRANSPOSED [b,h,32,L].
__global__ __launch_bounds__(256) void proj_gemm(
    const float* __restrict__ Xq, const float* __restrict__ Xk, const float* __restrict__ Xv,
    const float* __restrict__ Wq, const float* __restrict__ Wk, const float* __restrict__ Wv,
    const float* __restrict__ bq, const float* __restrict__ bk, const float* __restrict__ bv,
    f16* __restrict__ Qb, f16* __restrict__ Kb, f16* __restrict__ Vt)
{
    __shared__ f16 Wl[64 * WLS];   // 33 KB: W^T tile [n_local][k]
    const int p = blockIdx.z;
    const float* X = p == 0 ? Xq : p == 1 ? Xk : Xv;
    const float* W = p == 0 ? Wq : p == 1 ? Wk : Wv;
    const float* bias = p == 0 ? bq : p == 1 ? bk : bv;

    const int t = threadIdx.x, w = t >> 6, lane = t & 63;
    const int l15 = lane & 15, quad = lane >> 4;
    const int m0 = blockIdx.x * 64 + w * 16;
    const int n0 = blockIdx.y * 64;

    // stage W[k][n0+nl] -> Wl[nl][k] (f16). Coalesced 256B global rows.
    {
        const int nl = t & 63, kb = t >> 6;
        for (int kk = 0; kk < 64; ++kk) {
            const int k = kk * 4 + kb;
            Wl[nl * WLS + k] = (f16)W[(size_t)k * DIN + n0 + nl];
        }
    }
    __syncthreads();

    const float* Arow = X + (size_t)(m0 + l15) * DIN;

    f4 acc[4] = {{0.f,0.f,0.f,0.f},{0.f,0.f,0.f,0.f},{0.f,0.f,0.f,0.f},{0.f,0.f,0.f,0.f}};
    for (int k0 = 0; k0 < DIN; k0 += 32) {
        float4 xa = *(const float4*)(Arow + k0 + quad * 8);
        float4 xb = *(const float4*)(Arow + k0 + quad * 8 + 4);
        h8 af = { (f16)xa.x, (f16)xa.y, (f16)xa.z, (f16)xa.w,
                  (f16)xb.x, (f16)xb.y, (f16)xb.z, (f16)xb.w };
        #pragma unroll
        for (int tt = 0; tt < 4; ++tt) {
            h8 bf = *(const h8*)(Wl + (tt * 16 + l15) * WLS + k0 + quad * 8);
            acc[tt] = __builtin_amdgcn_mfma_f32_16x16x32_f16(af, bf, acc[tt], 0, 0, 0);
        }
    }
    #pragma unroll
    for (int tt = 0; tt < 4; ++tt) {
        const int c = n0 + tt * 16 + l15;            // 16-tile never straddles a head
        const float bb = bias[c];
        const int h = c >> 5, dd = c & 31;
        #pragma unroll
        for (int r = 0; r < 4; ++r) {
            const int row = m0 + quad * 4 + r;
            const int b = row >> 11, l = row & (Ln - 1);
            const float v = acc[tt][r] + bb;
            if (p == 0)
                Qb[(((size_t)(b * Hn + h)) * Ln + l) * DEPTH + dd] = (f16)(v * SCALE);
            else if (p == 1)
                Kb[(((size_t)(b * Hn + h)) * Ln + l) * DEPTH + dd] = (f16)v;
            else
                Vt[(((size_t)(b * Hn + h)) * DEPTH + dd) * Ln + l] = (f16)v;
        }
    }
}

// ---- Kernel 2: split-K MFMA flash attention, transposed scores. -----------
// Grid (hb=16, 128): block = 16 q-rows; wave w handles keys [w*512, w*512+512);
// partial (m,l,O) combined in LDS. Stats per-lane scalars (q = lane&15).
__global__ __launch_bounds__(256) void flash_mfma(
    const f16* __restrict__ Qb, const f16* __restrict__ Kb,
    const f16* __restrict__ Vt, const int* __restrict__ mask,
    f16* __restrict__ Ob)
{
    __shared__ f16 Ps[4][16 * 72];     // 9216 B, wave-private strips
    __shared__ float Os[4][32][17];    // 8704 B, partial O^T [w][d][q]
    __shared__ float mS[4][16], lS[4][16];
    const int t = threadIdx.x, w = t >> 6, lane = t & 63;
    const int l15 = lane & 15, quad = lane >> 4;
    const int hb = blockIdx.x;                 // h = hb&7, b = hb>>3; lid%8 = hb%8 (XCD)
    const int q0 = blockIdx.y * 16;
    const int b = hb >> 3;
    const f16* Qh = Qb + (size_t)hb * Ln * DEPTH;
    const f16* Kh = Kb + (size_t)hb * Ln * DEPTH;
    const f16* Vh = Vt + (size_t)hb * DEPTH * Ln;
    const int* mrow = mask + b * Ln;
    f16* Psw = &Ps[w][0];
    const int k_base = w * (Ln / 4);

    const h8 qf = *(const h8*)(Qh + (size_t)(q0 + l15) * DEPTH + quad * 8);  // B-frag

    f4 o0 = {0.f,0.f,0.f,0.f}, o1 = {0.f,0.f,0.f,0.f};
    float m_run = -INFINITY, l_run = 0.f;      // per-lane: q = q0 + l15

    for (int kt = 0; kt < Ln / 4 / 64; ++kt) {
        const int k0 = k_base + kt * 64;
        // ---- S^T = K.Q^T : lane holds 16 keys of column q=l15 ----
        f4 s[4];
        int4 mk4[4];
        #pragma unroll
        for (int tt = 0; tt < 4; ++tt) {
            h8 kf = *(const h8*)(Kh + (size_t)(k0 + tt * 16 + l15) * DEPTH + quad * 8);
            f4 z = {0.f, 0.f, 0.f, 0.f};
            s[tt] = __builtin_amdgcn_mfma_f32_16x16x32_f16(kf, qf, z, 0, 0, 0);
            mk4[tt] = *(const int4*)(mrow + k0 + tt * 16 + quad * 4);
        }
        // ---- mask + in-register max, 2-shuffle cross-quad reduce ----
        float rmax = -INFINITY;
        #pragma unroll
        for (int tt = 0; tt < 4; ++tt) {
            const int* mkp = (const int*)&mk4[tt];
            #pragma unroll
            for (int r = 0; r < 4; ++r) {
                const float v = mkp[r] ? s[tt][r] : NEGC;
                s[tt][r] = v;
                rmax = fmaxf(rmax, v);
            }
        }
        rmax = fmaxf(rmax, __shfl_xor(rmax, 16, 64));
        rmax = fmaxf(rmax, __shfl_xor(rmax, 32, 64));

        const float mn = fmaxf(m_run, rmax);
        const float alpha = __expf(m_run - mn);      // first tile: exp(-inf)=0
        m_run = mn;

        // ---- P = exp(S^T - m) -> packed 8B LDS stores; in-register sum ----
        float rsum = 0.f;
        #pragma unroll
        for (int tt = 0; tt < 4; ++tt) {
            h4 pk;
            #pragma unroll
            for (int r = 0; r < 4; ++r) {
                const float pv = __expf(s[tt][r] - mn);
                rsum += pv;
                pk[r] = (f16)pv;
            }
            *(h4*)(Psw + l15 * 72 + tt * 16 + quad * 4) = pk;   // P[q][key]
        }
        rsum += __shfl_xor(rsum, 16, 64);
        rsum += __shfl_xor(rsum, 32, 64);
        l_run = alpha * l_run + rsum;

        // ---- O^T = V^T.P : A = V^T (contig), B = P; alpha per-lane ----
        #pragma unroll
        for (int r = 0; r < 4; ++r) { o0[r] *= alpha; o1[r] *= alpha; }
        #pragma unroll
        for (int ks = 0; ks < 2; ++ks) {
            h8 pf = *(const h8*)(Psw + l15 * 72 + ks * 32 + quad * 8);      // B-frag
            h8 v0 = *(const h8*)(Vh + (size_t)l15 * Ln        + k0 + ks * 32 + quad * 8);
            h8 v1 = *(const h8*)(Vh + (size_t)(16 + l15) * Ln + k0 + ks * 32 + quad * 8);
            o0 = __builtin_amdgcn_mfma_f32_16x16x32_f16(v0, pf, o0, 0, 0, 0);
            o1 = __builtin_amdgcn_mfma_f32_16x16x32_f16(v1, pf, o1, 0, 0, 0);
        }
    }
    // ---- write wave partials ----
    if (quad == 0) { mS[w][l15] = m_run; lS[w][l15] = l_run; }
    #pragma unroll
    for (int r = 0; r < 4; ++r) {
        Os[w][quad * 4 + r][l15]      = o0[r];
        Os[w][16 + quad * 4 + r][l15] = o1[r];
    }
    __syncthreads();

    // ---- combine 4 chunks: thread -> (q = t&15, d = t>>4 and +16) ----
    {
        const int cq = t & 15, cd = t >> 4;
        const float m0 = mS[0][cq], m1 = mS[1][cq], m2 = mS[2][cq], m3 = mS[3][cq];
        const float ms = fmaxf(fmaxf(m0, m1), fmaxf(m2, m3));
        const float e0 = __expf(m0 - ms), e1 = __expf(m1 - ms);
        const float e2 = __expf(m2 - ms), e3 = __expf(m3 - ms);
        const float ls = e0 * lS[0][cq] + e1 * lS[1][cq] + e2 * lS[2][cq] + e3 * lS[3][cq];
        const float inv = 1.0f / ls;
        f16* Oq = Ob + ((size_t)hb * Ln + q0 + cq) * DEPTH;
        #pragma unroll
        for (int i = 0; i < 2; ++i) {
            const int dd = cd + 16 * i;
            const float ov = e0 * Os[0][dd][cq] + e1 * Os[1][dd][cq] +
                             e2 * Os[2][dd][cq] + e3 * Os[3][dd][cq];
            Oq[dd] = (f16)(ov * inv);
        }
    }
}

// ---- Kernel 3: out projection; Wo staged fp32->f16 transposed in LDS. -----
__global__ __launch_bounds__(256) void out_gemm(
    const f16* __restrict__ Ob, const float* __restrict__ Wo,
    const float* __restrict__ bo, float* __restrict__ out)
{
    __shared__ f16 Wl[64 * WLS];
    const int t = threadIdx.x, w = t >> 6, lane = t & 63;
    const int l15 = lane & 15, quad = lane >> 4;
    const int m0 = blockIdx.x * 64 + w * 16;
    const int n0 = blockIdx.y * 64;

    {
        const int nl = t & 63, kb = t >> 6;
        for (int kk = 0; kk < 64; ++kk) {
            const int k = kk * 4 + kb;
            Wl[nl * WLS + k] = (f16)Wo[(size_t)k * DIN + n0 + nl];
        }
    }
    __syncthreads();

    const int rA = m0 + l15, bA = rA >> 11, qA = rA & (Ln - 1);

    f4 acc[4] = {{0.f,0.f,0.f,0.f},{0.f,0.f,0.f,0.f},{0.f,0.f,0.f,0.f},{0.f,0.f,0.f,0.f}};
    for (int k0 = 0; k0 < DIN; k0 += 32) {
        const int h = k0 >> 5;                    // frag stays inside one head
        h8 af = *(const h8*)(Ob + (((size_t)(bA * Hn + h)) * Ln + qA) * DEPTH + quad * 8);
        #pragma unroll
        for (int tt = 0; tt < 4; ++tt) {
            h8 bf = *(const h8*)(Wl + (tt * 16 + l15) * WLS + k0 + quad * 8);
            acc[tt] = __builtin_amdgcn_mfma_f32_16x16x32_f16(af, bf, acc[tt], 0, 0, 0);
        }
    }
    #pragma unroll
    for (int tt = 0; tt < 4; ++tt) {
        const int c = n0 + tt * 16 + l15;
        const float bb = bo[c];
        #pragma unroll
        for (int r = 0; r < 4; ++r)
            out[(size_t)(m0 + quad * 4 + r) * DIN + c] = acc[tt][r] + bb;
    }
}

// ===========================================================================
// FALLBACK PATH (proven R4): fused kernel, zero workspace
// ===========================================================================
#define QT 128
#define KT 32
#define TS 34
#define SST (KT + 1)

__global__ __launch_bounds__(512) void fb_fused_attn(
    const float* __restrict__ Xq, const float* __restrict__ Xk,
    const float* __restrict__ Xv, const int* __restrict__ mask,
    const float* __restrict__ Wq, const float* __restrict__ bq,
    const float* __restrict__ Wk, const float* __restrict__ bk,
    const float* __restrict__ Wv, const float* __restrict__ bv,
    float* __restrict__ out)
{
    __shared__ float Qs[QT * TS];
    __shared__ float Ks[KT * TS];
    __shared__ float Vs[KT * TS];
    __shared__ float Ss[QT * SST];
    __shared__ float mrow[QT], lrow[QT], arow[QT];
    __shared__ int mk[KT];

    const int t = threadIdx.x;
    const int d = t & 31;
    const int rg = t >> 5;
    const int q0 = blockIdx.x * QT;
    const int h = blockIdx.y;
    const int b = blockIdx.z;
    const int hc = h * DEPTH + d;

    {
        const float bqv = bq[hc];
        for (int i = 0; i < 8; ++i) {
            const int r = rg + 16 * i;
            const float* x = Xq + ((size_t)(b * Ln + q0 + r)) * DIN;
            float acc = bqv;
            #pragma unroll 8
            for (int k = 0; k < DIN; ++k) acc = fmaf(x[k], Wq[k * DIN + hc], acc);
            Qs[r * TS + d] = acc * SCALE;
        }
    }
    if (t < QT) { mrow[t] = -INFINITY; lrow[t] = 0.f; }
    float o_acc[8];
    #pragma unroll
    for (int i = 0; i < 8; ++i) o_acc[i] = 0.f;

    const float bkv = bk[hc], bvv = bv[hc];

    for (int kt = 0; kt < Ln / KT; ++kt) {
        const int k0 = kt * KT;
        #pragma unroll
        for (int i = 0; i < 2; ++i) {
            const int r = rg + 16 * i;
            const float* xk = Xk + ((size_t)(b * Ln + k0 + r)) * DIN;
            const float* xv = Xv + ((size_t)(b * Ln + k0 + r)) * DIN;
            float aK = bkv, aV = bvv;
            #pragma unroll 4
            for (int k = 0; k < DIN; ++k) {
                aK = fmaf(xk[k], Wk[k * DIN + hc], aK);
                aV = fmaf(xv[k], Wv[k * DIN + hc], aV);
            }
            Ks[r * TS + d] = aK;
            Vs[r * TS + d] = aV;
        }
        if (t < KT) mk[t] = mask[b * Ln + k0 + t];
        __syncthreads();

        for (int idx = t; idx < QT * KT; idx += 512) {
            const int r = idx >> 5, k = idx & (KT - 1);
            const float2* qv = (const float2*)(Qs + r * TS);
            const float2* kv = (const float2*)(Ks + k * TS);
            float s = 0.f;
            #pragma unroll
            for (int j = 0; j < 16; ++j) {
                float2 a = qv[j], c = kv[j];
                s += a.x * c.x + a.y * c.y;
            }
            Ss[r * SST + k] = mk[k] ? s : NEGC;
        }
        __syncthreads();

        if (t < QT) {
            float tm = -INFINITY;
            #pragma unroll 8
            for (int k = 0; k < KT; ++k) tm = fmaxf(tm, Ss[t * SST + k]);
            const float nm = fmaxf(mrow[t], tm);
            arow[t] = __expf(mrow[t] - nm);
            mrow[t] = nm;
        }
        __syncthreads();

        for (int idx = t; idx < QT * KT; idx += 512) {
            const int r = idx >> 5, k = idx & (KT - 1);
            Ss[r * SST + k] = __expf(Ss[r * SST + k] - mrow[r]);
        }
        __syncthreads();

        if (t < QT) {
            float rs = 0.f;
            #pragma unroll 8
            for (int k = 0; k < KT; ++k) rs += Ss[t * SST + k];
            lrow[t] = arow[t] * lrow[t] + rs;
        }
        #pragma unroll
        for (int i = 0; i < 8; ++i) {
            const int r = rg + 16 * i;
            const float a = arow[r];
            float acc = o_acc[i] * a;
            const float* pr = Ss + r * SST;
            const float* vc = Vs + d;
            #pragma unroll 8
            for (int k = 0; k < KT; ++k) acc = fmaf(pr[k], vc[k * TS], acc);
            o_acc[i] = acc;
        }
        __syncthreads();
    }
    #pragma unroll
    for (int i = 0; i < 8; ++i) {
        const int r = rg + 16 * i;
        out[((size_t)(b * Ln + q0 + r)) * DIN + hc] = o_acc[i] / lrow[r];
    }
}

__global__ __launch_bounds__(256) void fb_out_proj(
    const float* __restrict__ Wo, const float* __restrict__ bo,
    float* __restrict__ out)
{
    __shared__ float xr[4][DIN];
    const int col = threadIdx.x;
    const int r0 = blockIdx.x * 4;
    #pragma unroll
    for (int rr = 0; rr < 4; ++rr)
        xr[rr][col] = out[(size_t)(r0 + rr) * DIN + col];
    __syncthreads();
    const float bb = bo[col];
    float a0 = bb, a1 = bb, a2 = bb, a3 = bb;
    #pragma unroll 4
    for (int k = 0; k < DIN; ++k) {
        const float w = Wo[k * DIN + col];
        a0 = fmaf(xr[0][k], w, a0);
        a1 = fmaf(xr[1][k], w, a1);
        a2 = fmaf(xr[2][k], w, a2);
        a3 = fmaf(xr[3][k], w, a3);
    }
    float* o = out + (size_t)r0 * DIN + col;
    o[0] = a0; o[DIN] = a1; o[2 * DIN] = a2; o[3 * DIN] = a3;
}

// ===========================================================================
extern "C" void kernel_launch(void* const* d_in, const int* in_sizes, int n_in,
                              void* d_out, int out_size, void* d_ws, size_t ws_size,
                              hipStream_t stream) {
    const float* Xq = (const float*)d_in[0];
    const float* Xk = (const float*)d_in[1];
    const float* Xv = (const float*)d_in[2];
    const int* mask = (const int*)d_in[3];
    const float* Wq = (const float*)d_in[4];
    const float* bq = (const float*)d_in[5];
    const float* Wk = (const float*)d_in[6];
    const float* bk = (const float*)d_in[7];
    const float* Wv = (const float*)d_in[8];
    const float* bv = (const float*)d_in[9];
    const float* Wo = (const float*)d_in[10];
    const float* bo = (const float*)d_in[11];
    float* out = (float*)d_out;

    const size_t HB_E = (size_t)Bn * Hn * Ln * DEPTH;     // 1M f16 each
    const size_t need = 3 * HB_E * sizeof(f16);           // 6 MB

    if (ws_size >= need) {
        f16* Qb = (f16*)d_ws;    // becomes O after flash_mfma
        f16* Kb = Qb + HB_E;
        f16* Vt = Kb + HB_E;
        proj_gemm<<<dim3(Bn * Ln / 64, DIN / 64, 3), 256, 0, stream>>>(
            Xq, Xk, Xv, Wq, Wk, Wv, bq, bk, bv, Qb, Kb, Vt);
        flash_mfma<<<dim3(Bn * Hn, Ln / 16), 256, 0, stream>>>(Qb, Kb, Vt, mask, Qb);
        out_gemm<<<dim3(Bn * Ln / 64, DIN / 64), 256, 0, stream>>>(Qb, Wo, bo, out);
    } else {
        fb_fused_attn<<<dim3(Ln / QT, Hn, Bn), 512, 0, stream>>>(
            Xq, Xk, Xv, mask, Wq, bq, Wk, bk, Wv, bv, out);
        fb_out_proj<<<Bn * Ln / 4, 256, 0, stream>>>(Wo, bo, out);
    }
}